// Round 3
// baseline (1446.212 us; speedup 1.0000x reference)
//
#include <hip/hip_runtime.h>
#include <hip/hip_bf16.h>

#define TT 2048
#define BB 512
#define HH 64

__device__ __forceinline__ float frcp(float x){ return __builtin_amdgcn_rcpf(x); }
__device__ __forceinline__ float fsig(float a){ return frcp(1.0f + __expf(-a)); }
__device__ __forceinline__ float ftanh(float a){ return 1.0f - 2.0f*frcp(__expf(2.0f*a)+1.0f); }
__device__ __forceinline__ float bcast(float v, int lane){
  return __uint_as_float((unsigned)__builtin_amdgcn_readlane((int)__float_as_uint(v), lane));
}

// One block = one batch row. 4 waves; wave q owns gate quad q (0:i 1:f 2:g 3:o).
// Lane j computes gate[q*64+j]: dot(Whh_row, h) with h broadcast lane->SGPR via
// readlane, weights pinned in 64 VGPRs/lane. One barrier/step, parity
// double-buffered LDS exchange of the 4 post-activation gate vectors.
// amdgpu_waves_per_eu(1,2): only 2 waves/SIMD can ever be resident
// (512 blocks x 4 waves / 1024 SIMDs) -> let regalloc use up to 256 VGPRs.
__global__ void __launch_bounds__(256)
__attribute__((amdgpu_waves_per_eu(1, 2)))
lstm_fwd_kernel(
    const float* __restrict__ x, const float* __restrict__ Wih,
    const float* __restrict__ Whh, const float* __restrict__ bih,
    const float* __restrict__ bhh, float* __restrict__ hout)
{
  const int b   = blockIdx.x;
  const int tid = threadIdx.x;
  const int q   = tid >> 6;      // gate quad
  const int j   = tid & 63;      // hidden index == lane
  const int g   = q*HH + j;

  // recurrent weight row -> 64 VGPRs, then sever from the loads so the
  // register allocator CANNOT rematerialize them inside the t-loop
  // (R1 post-mortem: VGPR_Count=44 proved it was re-loading every step).
  float w[HH];
  const float4* wrow = reinterpret_cast<const float4*>(Whh + (size_t)g*HH);
  #pragma unroll
  for (int k = 0; k < 16; k++){
    float4 a = wrow[k];
    w[4*k+0]=a.x; w[4*k+1]=a.y; w[4*k+2]=a.z; w[4*k+3]=a.w;
  }
  #pragma unroll
  for (int k = 0; k < HH; k++) asm volatile("" : "+v"(w[k]));

  float wi[7];
  #pragma unroll
  for (int k = 0; k < 7; k++) wi[k] = Wih[g*7+k];
  #pragma unroll
  for (int k = 0; k < 7; k++) asm volatile("" : "+v"(wi[k]));
  const float bias = bih[g] + bhh[g];

  __shared__ float ex[2][4][HH];   // parity x gate-quad x hidden

  float h = 0.0f, c = 0.0f;
  const float* xr = x + (size_t)b*TT*7;
  float xc[7];
  #pragma unroll
  for (int k = 0; k < 7; k++) xc[k] = xr[k];

  #pragma unroll 1
  for (int t = 0; t < TT; t++){
    // prefetch next step's x (uniform address; latency hidden by the dot)
    const float* xp1 = xr + (size_t)((t+1 < TT) ? (t+1) : t)*7;
    float xn[7];
    #pragma unroll
    for (int k = 0; k < 7; k++) xn[k] = xp1[k];

    float a0 = bias, a1 = 0.f, a2 = 0.f, a3 = 0.f;
    #pragma unroll
    for (int k = 0; k < 7; k++) a0 += xc[k]*wi[k];

    #pragma unroll
    for (int k = 0; k < HH; k += 4){
      const float h0 = bcast(h, k+0), h1 = bcast(h, k+1);
      const float h2 = bcast(h, k+2), h3 = bcast(h, k+3);
      a0 += h0*w[k+0];
      a1 += h1*w[k+1];
      a2 += h2*w[k+2];
      a3 += h3*w[k+3];
    }
    const float acc = (a0+a1)+(a2+a3);

    const float v = (q == 2) ? ftanh(acc) : fsig(acc);

    const int par = t & 1;
    ex[par][q][j] = v;
    __syncthreads();

    const float iv = ex[par][0][j];
    const float fv = ex[par][1][j];
    const float gv = ex[par][2][j];
    const float ov = ex[par][3][j];

    c = fv*c + iv*gv;
    h = ov*ftanh(c);

    #pragma unroll
    for (int k = 0; k < 7; k++) xc[k] = xn[k];
  }
  if (q == 0) hout[b*HH + j] = h;
}

// Backward direction contributes only ONE step (scan reverse=True: output at
// t=T-1 is the first reverse step from zero state => W_hh_b unused, c = i*g).
// Fused with the final linear layer.
__global__ __launch_bounds__(64, 1) void lstm_bwd_lin_kernel(
    const float* __restrict__ x,   const float* __restrict__ Wib,
    const float* __restrict__ bib, const float* __restrict__ bhb,
    const float* __restrict__ Wlin,const float* __restrict__ blin,
    const float* __restrict__ hf,  float* __restrict__ out)
{
  const int b = blockIdx.x;
  const int j = threadIdx.x;  // 0..63
  const float* xt = x + ((size_t)b*TT + (TT-1))*7;
  float xv[7];
  #pragma unroll
  for (int k = 0; k < 7; k++) xv[k] = xt[k];

  float g4[4];
  #pragma unroll
  for (int qq = 0; qq < 4; qq++){
    const int g = qq*HH + j;
    float a = bib[g] + bhb[g];
    #pragma unroll
    for (int k = 0; k < 7; k++) a += xv[k]*Wib[g*7+k];
    g4[qq] = a;
  }
  const float iv = fsig(g4[0]);
  const float gv = ftanh(g4[2]);
  const float ov = fsig(g4[3]);
  const float cc = iv*gv;          // f * c0 = 0
  const float hb = ov*ftanh(cc);
  const float hfv = hf[b*HH + j];

  float s[3];
  #pragma unroll
  for (int o = 0; o < 3; o++)
    s[o] = hfv*Wlin[o*128 + j] + hb*Wlin[o*128 + 64 + j];

  #pragma unroll
  for (int o = 0; o < 3; o++){
    float v = s[o];
    #pragma unroll
    for (int m = 32; m >= 1; m >>= 1) v += __shfl_xor(v, m, 64);
    s[o] = v;
  }
  if (j == 0){
    out[b*3+0] = s[0] + blin[0];
    out[b*3+1] = s[1] + blin[1];
    out[b*3+2] = s[2] + blin[2];
  }
}

extern "C" void kernel_launch(void* const* d_in, const int* in_sizes, int n_in,
                              void* d_out, int out_size, void* d_ws, size_t ws_size,
                              hipStream_t stream)
{
  const float* x    = (const float*)d_in[0];
  const float* Wihf = (const float*)d_in[1];
  const float* Whhf = (const float*)d_in[2];
  const float* bihf = (const float*)d_in[3];
  const float* bhhf = (const float*)d_in[4];
  const float* Wihb = (const float*)d_in[5];
  // d_in[6] (W_hh_b) is mathematically unused: backward state starts at zero
  const float* bibb = (const float*)d_in[7];
  const float* bhbb = (const float*)d_in[8];
  const float* Wlin = (const float*)d_in[9];
  const float* blin = (const float*)d_in[10];
  float* out = (float*)d_out;
  float* hf  = (float*)d_ws;   // [512,64] fp32 scratch

  lstm_fwd_kernel<<<BB, 256, 0, stream>>>(x, Wihf, Whhf, bihf, bhhf, hf);
  lstm_bwd_lin_kernel<<<BB, 64, 0, stream>>>(x, Wihb, bibb, bhbb, Wlin, blin, hf, out);
}

// Round 4
// 1416.158 us; speedup vs baseline: 1.0212x; 1.0212x over previous
//
#include <hip/hip_runtime.h>
#include <hip/hip_bf16.h>

#define TT 2048
#define BB 512
#define HH 64

__device__ __forceinline__ float frcp(float x){ return __builtin_amdgcn_rcpf(x); }
__device__ __forceinline__ float fsig(float a){ return frcp(1.0f + __expf(-a)); }
__device__ __forceinline__ float ftanh(float a){ return 1.0f - 2.0f*frcp(__expf(2.0f*a)+1.0f); }

// One block = one batch row. 4 waves; wave wv owns hidden units [16wv,16wv+16),
// computing ALL FOUR gates for them: lane l -> gate q=l>>4, unit j=16wv+(l&15).
// h broadcast to everyone via 16 uniform-address ds_read_b128 (LDS broadcast,
// conflict-free). Gate combine (i,f,g,o per unit) is 3 in-wave shuffles — the
// barrier'd LDS gate-exchange of R2 is gone. One barrier/step (publish h).
// g-gate weights pre-scaled by 2 so all lanes run one sigmoid-shaped path:
// tanh(a) = 2*sigmoid(2a) - 1  ->  v = s*sigmoid(acc) + (1-s), s in {1,2}.
__global__ void __launch_bounds__(256)
__attribute__((amdgpu_waves_per_eu(1, 2)))
lstm_fwd_kernel(
    const float* __restrict__ x, const float* __restrict__ Wih,
    const float* __restrict__ Whh, const float* __restrict__ bih,
    const float* __restrict__ bhh, float* __restrict__ hout)
{
  const int b   = blockIdx.x;
  const int tid = threadIdx.x;
  const int wv  = tid >> 6;
  const int l   = tid & 63;
  const int q   = l >> 4;          // 0:i 1:f 2:g 3:o
  const int u   = l & 15;
  const int j   = 16*wv + u;       // hidden unit
  const int gr  = q*HH + j;        // row in the 4H x H weight matrix

  const float s  = (q == 2) ? 2.0f : 1.0f;
  const float c1 = 1.0f - s;

  // recurrent weight row -> 64 pinned VGPRs (pre-scaled by s)
  float w[HH];
  {
    const float4* wrow = reinterpret_cast<const float4*>(Whh + (size_t)gr*HH);
    #pragma unroll
    for (int k = 0; k < 16; k++){
      float4 a = wrow[k];
      w[4*k+0]=a.x*s; w[4*k+1]=a.y*s; w[4*k+2]=a.z*s; w[4*k+3]=a.w*s;
    }
  }
  #pragma unroll
  for (int k = 0; k < HH; k++) asm volatile("" : "+v"(w[k]));

  float wi[7];
  #pragma unroll
  for (int k = 0; k < 7; k++) wi[k] = Wih[gr*7+k]*s;
  const float bias = (bih[gr] + bhh[gr])*s;

  __shared__ float hbuf[2][HH];    // parity double-buffered hidden state
  if (tid < HH){ hbuf[0][tid] = 0.0f; hbuf[1][tid] = 0.0f; }
  __syncthreads();

  float h = 0.0f, c = 0.0f;        // state for unit j (replicated over q)
  const float* xr = x + (size_t)b*TT*7;
  float xc[7];
  #pragma unroll
  for (int k = 0; k < 7; k++) xc[k] = xr[k];

  #pragma unroll 1
  for (int t = 0; t < TT; t++){
    const int par = t & 1;
    // prefetch next step's x (uniform address -> scalar loads, hidden by dot)
    const float* xp1 = xr + (size_t)((t+1 < TT) ? (t+1) : t)*7;
    float xn[7];
    #pragma unroll
    for (int k = 0; k < 7; k++) xn[k] = xp1[k];

    float a0 = bias, a1 = 0.f, a2 = 0.f, a3 = 0.f;
    #pragma unroll
    for (int k = 0; k < 7; k++) a0 += xc[k]*wi[k];

    const float4* hb = reinterpret_cast<const float4*>(&hbuf[par][0]);
    #pragma unroll
    for (int k = 0; k < 16; k++){
      const float4 hv = hb[k];    // uniform-address broadcast read
      a0 += hv.x*w[4*k+0];
      a1 += hv.y*w[4*k+1];
      a2 += hv.z*w[4*k+2];
      a3 += hv.w*w[4*k+3];
    }
    const float acc = (a0+a1)+(a2+a3);   // pre-scaled preactivation

    // unified activation
    const float e = __expf(-acc);
    const float r = frcp(1.0f + e);
    const float v = s*r + c1;            // sigmoid (s=1) or tanh (s=2)

    // in-wave gather of (i,f,g,o) for unit j: 3 shuffles + selects
    const float vx16 = __shfl_xor(v, 16, 64);
    const bool  odd  = (q & 1);
    const float p1 = odd ? vx16 : v;     // q<2: i ; q>=2: g
    const float p2 = odd ? v : vx16;     // q<2: f ; q>=2: o
    const float r1 = __shfl_xor(p1, 32, 64);
    const float r2 = __shfl_xor(p2, 32, 64);
    const bool  hi = (q >= 2);
    const float iv = hi ? r1 : p1;
    const float fv = hi ? r2 : p2;
    const float gv = hi ? p1 : r1;
    const float ov = hi ? p2 : r2;

    c = fv*c + iv*gv;
    const float e2 = __expf(-2.0f*c);
    const float th = frcp(1.0f + e2)*2.0f - 1.0f;
    h = ov*th;

    if (q == 0) hbuf[par^1][j] = h;      // publish h_t for next step
    __syncthreads();

    #pragma unroll
    for (int k = 0; k < 7; k++) xc[k] = xn[k];
  }
  if (q == 0) hout[b*HH + j] = h;
}

// Backward direction contributes only ONE step (scan reverse=True: output at
// t=T-1 is the first reverse step from zero state => W_hh_b unused, c = i*g).
// Fused with the final linear layer.
__global__ __launch_bounds__(64, 1) void lstm_bwd_lin_kernel(
    const float* __restrict__ x,   const float* __restrict__ Wib,
    const float* __restrict__ bib, const float* __restrict__ bhb,
    const float* __restrict__ Wlin,const float* __restrict__ blin,
    const float* __restrict__ hf,  float* __restrict__ out)
{
  const int b = blockIdx.x;
  const int j = threadIdx.x;  // 0..63
  const float* xt = x + ((size_t)b*TT + (TT-1))*7;
  float xv[7];
  #pragma unroll
  for (int k = 0; k < 7; k++) xv[k] = xt[k];

  float g4[4];
  #pragma unroll
  for (int qq = 0; qq < 4; qq++){
    const int g = qq*HH + j;
    float a = bib[g] + bhb[g];
    #pragma unroll
    for (int k = 0; k < 7; k++) a += xv[k]*Wib[g*7+k];
    g4[qq] = a;
  }
  const float iv = fsig(g4[0]);
  const float gv = ftanh(g4[2]);
  const float ov = fsig(g4[3]);
  const float cc = iv*gv;          // f * c0 = 0
  const float hb = ov*ftanh(cc);
  const float hfv = hf[b*HH + j];

  float s[3];
  #pragma unroll
  for (int o = 0; o < 3; o++)
    s[o] = hfv*Wlin[o*128 + j] + hb*Wlin[o*128 + 64 + j];

  #pragma unroll
  for (int o = 0; o < 3; o++){
    float v = s[o];
    #pragma unroll
    for (int m = 32; m >= 1; m >>= 1) v += __shfl_xor(v, m, 64);
    s[o] = v;
  }
  if (j == 0){
    out[b*3+0] = s[0] + blin[0];
    out[b*3+1] = s[1] + blin[1];
    out[b*3+2] = s[2] + blin[2];
  }
}

extern "C" void kernel_launch(void* const* d_in, const int* in_sizes, int n_in,
                              void* d_out, int out_size, void* d_ws, size_t ws_size,
                              hipStream_t stream)
{
  const float* x    = (const float*)d_in[0];
  const float* Wihf = (const float*)d_in[1];
  const float* Whhf = (const float*)d_in[2];
  const float* bihf = (const float*)d_in[3];
  const float* bhhf = (const float*)d_in[4];
  const float* Wihb = (const float*)d_in[5];
  // d_in[6] (W_hh_b) is mathematically unused: backward state starts at zero
  const float* bibb = (const float*)d_in[7];
  const float* bhbb = (const float*)d_in[8];
  const float* Wlin = (const float*)d_in[9];
  const float* blin = (const float*)d_in[10];
  float* out = (float*)d_out;
  float* hf  = (float*)d_ws;   // [512,64] fp32 scratch

  lstm_fwd_kernel<<<BB, 256, 0, stream>>>(x, Wihf, Whhf, bihf, bhhf, hf);
  lstm_bwd_lin_kernel<<<BB, 64, 0, stream>>>(x, Wihb, bibb, bhbb, Wlin, blin, hf, out);
}

// Round 5
// 1199.802 us; speedup vs baseline: 1.2054x; 1.1803x over previous
//
#include <hip/hip_runtime.h>
#include <hip/hip_bf16.h>

#define TT 2048
#define BB 512
#define HH 64

typedef _Float16 h2 __attribute__((ext_vector_type(2)));

__device__ __forceinline__ float frcp(float x){ return __builtin_amdgcn_rcpf(x); }
__device__ __forceinline__ float fsig(float a){ return frcp(1.0f + __expf(-a)); }
__device__ __forceinline__ float ftanh(float a){ return 1.0f - 2.0f*frcp(__expf(2.0f*a)+1.0f); }

// One WAVE per batch row; lane l owns hidden unit l and computes ALL FOUR of
// its gates. Recurrent weights live in-register as f16 pairs (128 VGPRs),
// consumed by v_dot2_f32_f16 (f16 products are exact in fp32; fp32 accum).
// h never leaves the wave: pack (h_2k, h_2k+1) -> half2, 32 readlanes -> SGPR,
// 128 dot2 per step. NO LDS, NO barriers, NO cross-wave traffic in the
// 2048-step serial chain (R1-R3 post-mortem: the barrier'd exchange was the
// unhidable ~1200 cyc/step stall).
__global__ void __launch_bounds__(64)
__attribute__((amdgpu_waves_per_eu(1, 2)))
lstm_fwd_kernel(
    const float* __restrict__ x, const float* __restrict__ Wih,
    const float* __restrict__ Whh, const float* __restrict__ bih,
    const float* __restrict__ bhh, float* __restrict__ hout)
{
  const int b = blockIdx.x;
  const int l = threadIdx.x;   // lane == hidden unit

  // ---- recurrent weights: 4 gate rows x 32 f16-pairs = 128 pinned VGPRs ----
  int wb[4][32];
  #pragma unroll
  for (int q = 0; q < 4; q++){
    const float4* wr = reinterpret_cast<const float4*>(Whh + (size_t)(q*HH + l)*HH);
    #pragma unroll
    for (int k = 0; k < 16; k++){
      float4 a = wr[k];
      h2 p0; p0[0] = (_Float16)a.x; p0[1] = (_Float16)a.y;
      h2 p1; p1[0] = (_Float16)a.z; p1[1] = (_Float16)a.w;
      wb[q][2*k+0] = __builtin_bit_cast(int, p0);
      wb[q][2*k+1] = __builtin_bit_cast(int, p1);
    }
  }
  #pragma unroll
  for (int q = 0; q < 4; q++)
    #pragma unroll
    for (int k = 0; k < 32; k++) asm volatile("" : "+v"(wb[q][k]));

  // input-projection weights (fp32) + fused bias
  float wi[4][7], bias[4];
  #pragma unroll
  for (int q = 0; q < 4; q++){
    const int g = q*HH + l;
    #pragma unroll
    for (int k = 0; k < 7; k++) wi[q][k] = Wih[g*7+k];
    bias[q] = bih[g] + bhh[g];
  }

  float h = 0.0f, c = 0.0f;
  const float* xr = x + (size_t)b*TT*7;
  float xc[7];
  #pragma unroll
  for (int k = 0; k < 7; k++) xc[k] = xr[k];

  #pragma unroll 1
  for (int t = 0; t < TT; t++){
    // prefetch next x (wave-uniform -> scalar loads; hidden under the dots)
    const float* xp1 = xr + (size_t)((t+1 < TT) ? (t+1) : t)*7;
    float xn[7];
    #pragma unroll
    for (int k = 0; k < 7; k++) xn[k] = xp1[k];

    // pack (h_even, h_odd) pairs: even lane 2k holds (h_2k, h_2k+1)
    const float hn = __shfl_xor(h, 1, 64);
    h2 hp;
    hp[0] = (_Float16)((l & 1) ? hn : h);
    hp[1] = (_Float16)((l & 1) ? h  : hn);
    const int hpi = __builtin_bit_cast(int, hp);

    float a0 = bias[0], a1 = bias[1], a2 = bias[2], a3 = bias[3];
    #pragma unroll
    for (int k = 0; k < 7; k++){
      a0 += xc[k]*wi[0][k];
      a1 += xc[k]*wi[1][k];
      a2 += xc[k]*wi[2][k];
      a3 += xc[k]*wi[3][k];
    }

    #pragma unroll
    for (int k = 0; k < 32; k++){
      const int  hk = __builtin_amdgcn_readlane(hpi, 2*k);   // uniform pair
      const h2   hh = __builtin_bit_cast(h2, hk);
      a0 = __builtin_amdgcn_fdot2(__builtin_bit_cast(h2, wb[0][k]), hh, a0, false);
      a1 = __builtin_amdgcn_fdot2(__builtin_bit_cast(h2, wb[1][k]), hh, a1, false);
      a2 = __builtin_amdgcn_fdot2(__builtin_bit_cast(h2, wb[2][k]), hh, a2, false);
      a3 = __builtin_amdgcn_fdot2(__builtin_bit_cast(h2, wb[3][k]), hh, a3, false);
    }

    const float iv = fsig(a0);
    const float fv = fsig(a1);
    const float gv = ftanh(a2);
    const float ov = fsig(a3);

    c = fv*c + iv*gv;
    h = ov*ftanh(c);

    #pragma unroll
    for (int k = 0; k < 7; k++) xc[k] = xn[k];
  }
  hout[b*HH + l] = h;
}

// Backward direction contributes only ONE step (scan reverse=True: output at
// t=T-1 is the first reverse step from zero state => W_hh_b unused, c = i*g).
// Fused with the final linear layer.
__global__ __launch_bounds__(64, 1) void lstm_bwd_lin_kernel(
    const float* __restrict__ x,   const float* __restrict__ Wib,
    const float* __restrict__ bib, const float* __restrict__ bhb,
    const float* __restrict__ Wlin,const float* __restrict__ blin,
    const float* __restrict__ hf,  float* __restrict__ out)
{
  const int b = blockIdx.x;
  const int j = threadIdx.x;  // 0..63
  const float* xt = x + ((size_t)b*TT + (TT-1))*7;
  float xv[7];
  #pragma unroll
  for (int k = 0; k < 7; k++) xv[k] = xt[k];

  float g4[4];
  #pragma unroll
  for (int qq = 0; qq < 4; qq++){
    const int g = qq*HH + j;
    float a = bib[g] + bhb[g];
    #pragma unroll
    for (int k = 0; k < 7; k++) a += xv[k]*Wib[g*7+k];
    g4[qq] = a;
  }
  const float iv = fsig(g4[0]);
  const float gv = ftanh(g4[2]);
  const float ov = fsig(g4[3]);
  const float cc = iv*gv;          // f * c0 = 0
  const float hb = ov*ftanh(cc);
  const float hfv = hf[b*HH + j];

  float s[3];
  #pragma unroll
  for (int o = 0; o < 3; o++)
    s[o] = hfv*Wlin[o*128 + j] + hb*Wlin[o*128 + 64 + j];

  #pragma unroll
  for (int o = 0; o < 3; o++){
    float v = s[o];
    #pragma unroll
    for (int m = 32; m >= 1; m >>= 1) v += __shfl_xor(v, m, 64);
    s[o] = v;
  }
  if (j == 0){
    out[b*3+0] = s[0] + blin[0];
    out[b*3+1] = s[1] + blin[1];
    out[b*3+2] = s[2] + blin[2];
  }
}

extern "C" void kernel_launch(void* const* d_in, const int* in_sizes, int n_in,
                              void* d_out, int out_size, void* d_ws, size_t ws_size,
                              hipStream_t stream)
{
  const float* x    = (const float*)d_in[0];
  const float* Wihf = (const float*)d_in[1];
  const float* Whhf = (const float*)d_in[2];
  const float* bihf = (const float*)d_in[3];
  const float* bhhf = (const float*)d_in[4];
  const float* Wihb = (const float*)d_in[5];
  // d_in[6] (W_hh_b) is mathematically unused: backward state starts at zero
  const float* bibb = (const float*)d_in[7];
  const float* bhbb = (const float*)d_in[8];
  const float* Wlin = (const float*)d_in[9];
  const float* blin = (const float*)d_in[10];
  float* out = (float*)d_out;
  float* hf  = (float*)d_ws;   // [512,64] fp32 scratch

  lstm_fwd_kernel<<<BB, 64, 0, stream>>>(x, Wihf, Whhf, bihf, bhhf, hf);
  lstm_bwd_lin_kernel<<<BB, 64, 0, stream>>>(x, Wihb, bibb, bhbb, Wlin, blin, hf, out);
}

// Round 6
// 1161.926 us; speedup vs baseline: 1.2447x; 1.0326x over previous
//
#include <hip/hip_runtime.h>
#include <hip/hip_bf16.h>

#define TT 2048
#define BB 512
#define HH 64
#define CH 128            // timesteps per LDS x-chunk
#define NCH (TT/CH)       // 16 chunks

typedef _Float16 h2 __attribute__((ext_vector_type(2)));

__device__ __forceinline__ float frcp(float x){ return __builtin_amdgcn_rcpf(x); }
__device__ __forceinline__ float fsig(float a){ return frcp(1.0f + __expf(-a)); }
__device__ __forceinline__ float ftanh(float a){ return 1.0f - 2.0f*frcp(__expf(2.0f*a)+1.0f); }

// HBM -> LDS direct copy, one dword per lane
#define GLOAD_LDS_DW(gsrc, ldst) \
  __builtin_amdgcn_global_load_lds( \
      (const __attribute__((address_space(1))) unsigned int*)(gsrc), \
      (__attribute__((address_space(3))) unsigned int*)(ldst), 4, 0, 0)

// One WAVE per batch row; lane l owns hidden unit l, computes all 4 gates via
// v_dot2_f32_f16 on in-register f16 weight pairs. h stays in the wave
// (readlane broadcast). x is staged HBM->LDS in 128-step double-buffered
// chunks (global_load_lds issued a full chunk ahead), and per-step x comes
// from uniform-address ds_read prefetched one step ahead — NO global/scalar
// memory latency inside the 2048-step serial chain (R4 post-mortem: sunk
// s_loads of x were exposing L2/HBM latency every step).
__global__ void __launch_bounds__(64)
__attribute__((amdgpu_waves_per_eu(1, 2)))
lstm_fwd_kernel(
    const float* __restrict__ x, const float* __restrict__ Wih,
    const float* __restrict__ Whh, const float* __restrict__ bih,
    const float* __restrict__ bhh, float* __restrict__ hout)
{
  const int b = blockIdx.x;
  const int l = threadIdx.x;   // lane == hidden unit

  __shared__ float xs[2][CH*7];          // 2 x 3584 B x-staging buffers

  const float* xr = x + (size_t)b*TT*7;

  // issue chunk 0 staging (14 x 256B = 896 dwords = 128 steps x 7)
  #pragma unroll
  for (int i = 0; i < 14; i++)
    GLOAD_LDS_DW(xr + i*64 + l, &xs[0][i*64 + l]);

  // ---- recurrent weights: 4 gate rows x 32 f16-pairs = 128 pinned VGPRs ----
  int wb[4][32];
  #pragma unroll
  for (int q = 0; q < 4; q++){
    const float4* wr = reinterpret_cast<const float4*>(Whh + (size_t)(q*HH + l)*HH);
    #pragma unroll
    for (int k = 0; k < 16; k++){
      float4 a = wr[k];
      h2 p0; p0[0] = (_Float16)a.x; p0[1] = (_Float16)a.y;
      h2 p1; p1[0] = (_Float16)a.z; p1[1] = (_Float16)a.w;
      wb[q][2*k+0] = __builtin_bit_cast(int, p0);
      wb[q][2*k+1] = __builtin_bit_cast(int, p1);
    }
  }
  #pragma unroll
  for (int q = 0; q < 4; q++)
    #pragma unroll
    for (int k = 0; k < 32; k++) asm volatile("" : "+v"(wb[q][k]));

  // input-projection weights (fp32) + fused bias — pinned too (R4: wi was
  // being rematerialized per step; VGPR_Count=124 < 128 proved demotion)
  float wi[4][7], bias[4];
  #pragma unroll
  for (int q = 0; q < 4; q++){
    const int g = q*HH + l;
    #pragma unroll
    for (int k = 0; k < 7; k++) wi[q][k] = Wih[g*7+k];
    bias[q] = bih[g] + bhh[g];
  }
  #pragma unroll
  for (int q = 0; q < 4; q++){
    #pragma unroll
    for (int k = 0; k < 7; k++) asm volatile("" : "+v"(wi[q][k]));
    asm volatile("" : "+v"(bias[q]));
  }

  float h = 0.0f, c = 0.0f;

  #pragma unroll 1
  for (int ck = 0; ck < NCH; ck++){
    // buffer for this chunk was issued a full chunk ago -> wait is free
    asm volatile("s_waitcnt vmcnt(0)" ::: "memory");
    // issue next chunk's staging now: ~128 steps of compute to cover it
    if (ck + 1 < NCH){
      const float* src = xr + (size_t)(ck+1)*CH*7;
      float* dst = &xs[(ck+1)&1][0];
      #pragma unroll
      for (int i = 0; i < 14; i++)
        GLOAD_LDS_DW(src + i*64 + l, dst + i*64 + l);
    }
    const float* xsbuf = &xs[ck & 1][0];

    // first step's x of this chunk (in-chain once per 128 steps)
    float xc[7];
    #pragma unroll
    for (int k = 0; k < 7; k++) xc[k] = xsbuf[k];

    #pragma unroll 2
    for (int s = 0; s < CH; s++){
      // prefetch next step's x from LDS (uniform-address broadcast reads)
      const int nxt = (s+1 < CH) ? (s+1) : s;
      float xn[7];
      #pragma unroll
      for (int k = 0; k < 7; k++) xn[k] = xsbuf[nxt*7 + k];

      // pack (h_even, h_odd) pairs: even lane 2k holds (h_2k, h_2k+1)
      const float hn = __shfl_xor(h, 1, 64);
      h2 hp;
      hp[0] = (_Float16)((l & 1) ? hn : h);
      hp[1] = (_Float16)((l & 1) ? h  : hn);
      const int hpi = __builtin_bit_cast(int, hp);

      float a0 = bias[0], a1 = bias[1], a2 = bias[2], a3 = bias[3];
      #pragma unroll
      for (int k = 0; k < 7; k++){
        a0 += xc[k]*wi[0][k];
        a1 += xc[k]*wi[1][k];
        a2 += xc[k]*wi[2][k];
        a3 += xc[k]*wi[3][k];
      }

      #pragma unroll
      for (int k = 0; k < 32; k++){
        const int hk = __builtin_amdgcn_readlane(hpi, 2*k);   // uniform pair
        const h2  hh = __builtin_bit_cast(h2, hk);
        a0 = __builtin_amdgcn_fdot2(__builtin_bit_cast(h2, wb[0][k]), hh, a0, false);
        a1 = __builtin_amdgcn_fdot2(__builtin_bit_cast(h2, wb[1][k]), hh, a1, false);
        a2 = __builtin_amdgcn_fdot2(__builtin_bit_cast(h2, wb[2][k]), hh, a2, false);
        a3 = __builtin_amdgcn_fdot2(__builtin_bit_cast(h2, wb[3][k]), hh, a3, false);
      }

      const float iv = fsig(a0);
      const float fv = fsig(a1);
      const float gv = ftanh(a2);
      const float ov = fsig(a3);

      c = fv*c + iv*gv;
      h = ov*ftanh(c);

      #pragma unroll
      for (int k = 0; k < 7; k++) xc[k] = xn[k];
    }
  }
  hout[b*HH + l] = h;
}

// Backward direction contributes only ONE step (scan reverse=True: output at
// t=T-1 is the first reverse step from zero state => W_hh_b unused, c = i*g).
// Fused with the final linear layer.
__global__ __launch_bounds__(64, 1) void lstm_bwd_lin_kernel(
    const float* __restrict__ x,   const float* __restrict__ Wib,
    const float* __restrict__ bib, const float* __restrict__ bhb,
    const float* __restrict__ Wlin,const float* __restrict__ blin,
    const float* __restrict__ hf,  float* __restrict__ out)
{
  const int b = blockIdx.x;
  const int j = threadIdx.x;  // 0..63
  const float* xt = x + ((size_t)b*TT + (TT-1))*7;
  float xv[7];
  #pragma unroll
  for (int k = 0; k < 7; k++) xv[k] = xt[k];

  float g4[4];
  #pragma unroll
  for (int qq = 0; qq < 4; qq++){
    const int g = qq*HH + j;
    float a = bib[g] + bhb[g];
    #pragma unroll
    for (int k = 0; k < 7; k++) a += xv[k]*Wib[g*7+k];
    g4[qq] = a;
  }
  const float iv = fsig(g4[0]);
  const float gv = ftanh(g4[2]);
  const float ov = fsig(g4[3]);
  const float cc = iv*gv;          // f * c0 = 0
  const float hb = ov*ftanh(cc);
  const float hfv = hf[b*HH + j];

  float s[3];
  #pragma unroll
  for (int o = 0; o < 3; o++)
    s[o] = hfv*Wlin[o*128 + j] + hb*Wlin[o*128 + 64 + j];

  #pragma unroll
  for (int o = 0; o < 3; o++){
    float v = s[o];
    #pragma unroll
    for (int m = 32; m >= 1; m >>= 1) v += __shfl_xor(v, m, 64);
    s[o] = v;
  }
  if (j == 0){
    out[b*3+0] = s[0] + blin[0];
    out[b*3+1] = s[1] + blin[1];
    out[b*3+2] = s[2] + blin[2];
  }
}

extern "C" void kernel_launch(void* const* d_in, const int* in_sizes, int n_in,
                              void* d_out, int out_size, void* d_ws, size_t ws_size,
                              hipStream_t stream)
{
  const float* x    = (const float*)d_in[0];
  const float* Wihf = (const float*)d_in[1];
  const float* Whhf = (const float*)d_in[2];
  const float* bihf = (const float*)d_in[3];
  const float* bhhf = (const float*)d_in[4];
  const float* Wihb = (const float*)d_in[5];
  // d_in[6] (W_hh_b) is mathematically unused: backward state starts at zero
  const float* bibb = (const float*)d_in[7];
  const float* bhbb = (const float*)d_in[8];
  const float* Wlin = (const float*)d_in[9];
  const float* blin = (const float*)d_in[10];
  float* out = (float*)d_out;
  float* hf  = (float*)d_ws;   // [512,64] fp32 scratch

  lstm_fwd_kernel<<<BB, 64, 0, stream>>>(x, Wihf, Whhf, bihf, bhhf, hf);
  lstm_bwd_lin_kernel<<<BB, 64, 0, stream>>>(x, Wihb, bibb, bhbb, Wlin, blin, hf, out);
}

// Round 7
// 1132.930 us; speedup vs baseline: 1.2765x; 1.0256x over previous
//
#include <hip/hip_runtime.h>
#include <hip/hip_bf16.h>

#define TT 2048
#define BB 512
#define HH 64
#define CH 128            // timesteps per LDS x-chunk
#define NCH (TT/CH)       // 16 chunks

typedef _Float16 h2 __attribute__((ext_vector_type(2)));

__device__ __forceinline__ float frcp(float x){ return __builtin_amdgcn_rcpf(x); }
__device__ __forceinline__ float fsig(float a){ return frcp(1.0f + __expf(-a)); }
__device__ __forceinline__ float ftanh(float a){ return 1.0f - 2.0f*frcp(__expf(2.0f*a)+1.0f); }

// HBM -> LDS direct copy, one dword per lane
#define GLOAD_LDS_DW(gsrc, ldst) \
  __builtin_amdgcn_global_load_lds( \
      (const __attribute__((address_space(1))) unsigned int*)(gsrc), \
      (__attribute__((address_space(3))) unsigned int*)(ldst), 4, 0, 0)

// One WAVE per batch row; lane l owns hidden unit l, computes all 4 gates via
// v_dot2_f32_f16 on in-register f16 weight pairs; h broadcast by readlane.
// R5 post-mortem: with waves_per_eu(1,2) the allocator parked the 128 weight
// regs in AGPRs (VGPR_Count=124 < live set ~190, no scratch traffic) and
// bounced them through v_accvgpr_read every step (~+128 instr/step).
// waves_per_eu(1,1): only 1 wave/SIMD ever resident (512 waves vs 1024 SIMDs),
// so give the allocator the full single-wave register file (~512, m08) and
// keep the weights as direct dot2 operands.
__global__ void __launch_bounds__(64)
__attribute__((amdgpu_waves_per_eu(1, 1)))
lstm_fwd_kernel(
    const float* __restrict__ x, const float* __restrict__ Wih,
    const float* __restrict__ Whh, const float* __restrict__ bih,
    const float* __restrict__ bhh, float* __restrict__ hout)
{
  const int b = blockIdx.x;
  const int l = threadIdx.x;   // lane == hidden unit

  __shared__ float xs[2][CH*7];          // 2 x 3584 B x-staging buffers

  const float* xr = x + (size_t)b*TT*7;

  // issue chunk 0 staging (14 x 256B = 896 dwords = 128 steps x 7)
  #pragma unroll
  for (int i = 0; i < 14; i++)
    GLOAD_LDS_DW(xr + i*64 + l, &xs[0][i*64 + l]);

  // ---- recurrent weights: 4 gate rows x 32 f16-pairs = 128 pinned VGPRs ----
  int wb[4][32];
  #pragma unroll
  for (int q = 0; q < 4; q++){
    const float4* wr = reinterpret_cast<const float4*>(Whh + (size_t)(q*HH + l)*HH);
    #pragma unroll
    for (int k = 0; k < 16; k++){
      float4 a = wr[k];
      h2 p0; p0[0] = (_Float16)a.x; p0[1] = (_Float16)a.y;
      h2 p1; p1[0] = (_Float16)a.z; p1[1] = (_Float16)a.w;
      wb[q][2*k+0] = __builtin_bit_cast(int, p0);
      wb[q][2*k+1] = __builtin_bit_cast(int, p1);
    }
  }
  #pragma unroll
  for (int q = 0; q < 4; q++)
    #pragma unroll
    for (int k = 0; k < 32; k++) asm volatile("" : "+v"(wb[q][k]));

  // input-projection weights (fp32) + fused bias, pinned
  float wi[4][7], bias[4];
  #pragma unroll
  for (int q = 0; q < 4; q++){
    const int g = q*HH + l;
    #pragma unroll
    for (int k = 0; k < 7; k++) wi[q][k] = Wih[g*7+k];
    bias[q] = bih[g] + bhh[g];
  }
  #pragma unroll
  for (int q = 0; q < 4; q++){
    #pragma unroll
    for (int k = 0; k < 7; k++) asm volatile("" : "+v"(wi[q][k]));
    asm volatile("" : "+v"(bias[q]));
  }

  float h = 0.0f, c = 0.0f;

  #pragma unroll 1
  for (int ck = 0; ck < NCH; ck++){
    // buffer for this chunk was issued a full chunk ago -> wait is free
    asm volatile("s_waitcnt vmcnt(0)" ::: "memory");
    // issue next chunk's staging now: ~128 steps of compute to cover it
    if (ck + 1 < NCH){
      const float* src = xr + (size_t)(ck+1)*CH*7;
      float* dst = &xs[(ck+1)&1][0];
      #pragma unroll
      for (int i = 0; i < 14; i++)
        GLOAD_LDS_DW(src + i*64 + l, dst + i*64 + l);
    }
    const float* xsbuf = &xs[ck & 1][0];

    // first step's x of this chunk (in-chain once per 128 steps)
    float xc[7];
    #pragma unroll
    for (int k = 0; k < 7; k++) xc[k] = xsbuf[k];

    #pragma unroll 2
    for (int s = 0; s < CH; s++){
      // prefetch next step's x from LDS (uniform-address broadcast reads)
      const int nxt = (s+1 < CH) ? (s+1) : s;
      float xn[7];
      #pragma unroll
      for (int k = 0; k < 7; k++) xn[k] = xsbuf[nxt*7 + k];

      // pair packing: readlane only samples EVEN lanes, so lane 2k just needs
      // (h_2k, h_2k+1) — odd lanes' hp is dead, no order-select needed
      const float hn = __shfl_xor(h, 1, 64);
      h2 hp; hp[0] = (_Float16)h; hp[1] = (_Float16)hn;
      const int hpi = __builtin_bit_cast(int, hp);

      float a0 = bias[0], a1 = bias[1], a2 = bias[2], a3 = bias[3];
      #pragma unroll
      for (int k = 0; k < 7; k++){
        a0 += xc[k]*wi[0][k];
        a1 += xc[k]*wi[1][k];
        a2 += xc[k]*wi[2][k];
        a3 += xc[k]*wi[3][k];
      }

      #pragma unroll
      for (int k = 0; k < 32; k++){
        const int hk = __builtin_amdgcn_readlane(hpi, 2*k);   // uniform pair
        const h2  hh = __builtin_bit_cast(h2, hk);
        a0 = __builtin_amdgcn_fdot2(__builtin_bit_cast(h2, wb[0][k]), hh, a0, false);
        a1 = __builtin_amdgcn_fdot2(__builtin_bit_cast(h2, wb[1][k]), hh, a1, false);
        a2 = __builtin_amdgcn_fdot2(__builtin_bit_cast(h2, wb[2][k]), hh, a2, false);
        a3 = __builtin_amdgcn_fdot2(__builtin_bit_cast(h2, wb[3][k]), hh, a3, false);
      }

      const float iv = fsig(a0);
      const float fv = fsig(a1);
      const float gv = ftanh(a2);
      const float ov = fsig(a3);

      c = fv*c + iv*gv;
      h = ov*ftanh(c);

      #pragma unroll
      for (int k = 0; k < 7; k++) xc[k] = xn[k];
    }
  }
  hout[b*HH + l] = h;
}

// Backward direction contributes only ONE step (scan reverse=True: output at
// t=T-1 is the first reverse step from zero state => W_hh_b unused, c = i*g).
// Fused with the final linear layer.
__global__ __launch_bounds__(64, 1) void lstm_bwd_lin_kernel(
    const float* __restrict__ x,   const float* __restrict__ Wib,
    const float* __restrict__ bib, const float* __restrict__ bhb,
    const float* __restrict__ Wlin,const float* __restrict__ blin,
    const float* __restrict__ hf,  float* __restrict__ out)
{
  const int b = blockIdx.x;
  const int j = threadIdx.x;  // 0..63
  const float* xt = x + ((size_t)b*TT + (TT-1))*7;
  float xv[7];
  #pragma unroll
  for (int k = 0; k < 7; k++) xv[k] = xt[k];

  float g4[4];
  #pragma unroll
  for (int qq = 0; qq < 4; qq++){
    const int g = qq*HH + j;
    float a = bib[g] + bhb[g];
    #pragma unroll
    for (int k = 0; k < 7; k++) a += xv[k]*Wib[g*7+k];
    g4[qq] = a;
  }
  const float iv = fsig(g4[0]);
  const float gv = ftanh(g4[2]);
  const float ov = fsig(g4[3]);
  const float cc = iv*gv;          // f * c0 = 0
  const float hb = ov*ftanh(cc);
  const float hfv = hf[b*HH + j];

  float s[3];
  #pragma unroll
  for (int o = 0; o < 3; o++)
    s[o] = hfv*Wlin[o*128 + j] + hb*Wlin[o*128 + 64 + j];

  #pragma unroll
  for (int o = 0; o < 3; o++){
    float v = s[o];
    #pragma unroll
    for (int m = 32; m >= 1; m >>= 1) v += __shfl_xor(v, m, 64);
    s[o] = v;
  }
  if (j == 0){
    out[b*3+0] = s[0] + blin[0];
    out[b*3+1] = s[1] + blin[1];
    out[b*3+2] = s[2] + blin[2];
  }
}

extern "C" void kernel_launch(void* const* d_in, const int* in_sizes, int n_in,
                              void* d_out, int out_size, void* d_ws, size_t ws_size,
                              hipStream_t stream)
{
  const float* x    = (const float*)d_in[0];
  const float* Wihf = (const float*)d_in[1];
  const float* Whhf = (const float*)d_in[2];
  const float* bihf = (const float*)d_in[3];
  const float* bhhf = (const float*)d_in[4];
  const float* Wihb = (const float*)d_in[5];
  // d_in[6] (W_hh_b) is mathematically unused: backward state starts at zero
  const float* bibb = (const float*)d_in[7];
  const float* bhbb = (const float*)d_in[8];
  const float* Wlin = (const float*)d_in[9];
  const float* blin = (const float*)d_in[10];
  float* out = (float*)d_out;
  float* hf  = (float*)d_ws;   // [512,64] fp32 scratch

  lstm_fwd_kernel<<<BB, 64, 0, stream>>>(x, Wihf, Whhf, bihf, bhhf, hf);
  lstm_bwd_lin_kernel<<<BB, 64, 0, stream>>>(x, Wihb, bibb, bhbb, Wlin, blin, hf, out);
}

// Round 8
// 859.599 us; speedup vs baseline: 1.6824x; 1.3180x over previous
//
#include <hip/hip_runtime.h>
#include <hip/hip_bf16.h>

#define TT 2048
#define BB 512
#define HH 64
#define CH 128            // timesteps per LDS x-chunk
#define NCH (TT/CH)       // 16 chunks

typedef _Float16 h2 __attribute__((ext_vector_type(2)));

__device__ __forceinline__ float frcp(float x){ return __builtin_amdgcn_rcpf(x); }
__device__ __forceinline__ float fsig(float a){ return frcp(1.0f + __expf(-a)); }
__device__ __forceinline__ float ftanh(float a){ return 1.0f - 2.0f*frcp(__expf(2.0f*a)+1.0f); }

// HBM -> LDS direct copy, one dword per lane
#define GLOAD_LDS_DW(gsrc, ldst) \
  __builtin_amdgcn_global_load_lds( \
      (const __attribute__((address_space(1))) unsigned int*)(gsrc), \
      (__attribute__((address_space(3))) unsigned int*)(ldst), 4, 0, 0)

// One WAVE per batch row; lane l owns hidden unit l, computes all 4 gates via
// v_dot2_f32_f16 on in-register f16 weight pairs.
// R7 change: h-broadcast via SAME-WAVE LDS round-trip instead of
// readlane/shfl. End of step: lane l writes h_l as f16 (ds_write_b16).
// Start of step: 8 uniform-address ds_read_b128 return all 32 (h_2k,h_2k+1)
// f16 pairs, feeding dot2 directly. No barriers (single wave), no
// VALU->SGPR->VALU hazard stalls, no shfl_xor in the serial chain, no
// pack/cvt glue (R6 post-mortem: ~460 dynamic instr/step at 67% duty —
// readlane machinery and its hazards were the best candidate for the 2x
// instruction overhead + stall fraction).
__global__ void __launch_bounds__(64)
__attribute__((amdgpu_waves_per_eu(1, 1)))
lstm_fwd_kernel(
    const float* __restrict__ x, const float* __restrict__ Wih,
    const float* __restrict__ Whh, const float* __restrict__ bih,
    const float* __restrict__ bhh, float* __restrict__ hout)
{
  const int b = blockIdx.x;
  const int l = threadIdx.x;   // lane == hidden unit

  __shared__ float xs[2][CH*7];          // 2 x 3584 B x-staging buffers
  __shared__ unsigned int hlds[HH/2];    // h as f16[64] = 32 dwords

  const float* xr = x + (size_t)b*TT*7;

  // issue chunk 0 staging (14 x 256B = 896 dwords = 128 steps x 7)
  #pragma unroll
  for (int i = 0; i < 14; i++)
    GLOAD_LDS_DW(xr + i*64 + l, &xs[0][i*64 + l]);

  // ---- recurrent weights: 4 gate rows x 32 f16-pairs = 128 pinned VGPRs ----
  int wb[4][32];
  #pragma unroll
  for (int q = 0; q < 4; q++){
    const float4* wr = reinterpret_cast<const float4*>(Whh + (size_t)(q*HH + l)*HH);
    #pragma unroll
    for (int k = 0; k < 16; k++){
      float4 a = wr[k];
      h2 p0; p0[0] = (_Float16)a.x; p0[1] = (_Float16)a.y;
      h2 p1; p1[0] = (_Float16)a.z; p1[1] = (_Float16)a.w;
      wb[q][2*k+0] = __builtin_bit_cast(int, p0);
      wb[q][2*k+1] = __builtin_bit_cast(int, p1);
    }
  }
  #pragma unroll
  for (int q = 0; q < 4; q++)
    #pragma unroll
    for (int k = 0; k < 32; k++) asm volatile("" : "+v"(wb[q][k]));

  // input-projection weights (fp32) + fused bias, pinned
  float wi[4][7], bias[4];
  #pragma unroll
  for (int q = 0; q < 4; q++){
    const int g = q*HH + l;
    #pragma unroll
    for (int k = 0; k < 7; k++) wi[q][k] = Wih[g*7+k];
    bias[q] = bih[g] + bhh[g];
  }
  #pragma unroll
  for (int q = 0; q < 4; q++){
    #pragma unroll
    for (int k = 0; k < 7; k++) asm volatile("" : "+v"(wi[q][k]));
    asm volatile("" : "+v"(bias[q]));
  }

  // h_0 = 0: init the f16 h vector in LDS (lanes 0..31 cover 32 dwords)
  if (l < HH/2) hlds[l] = 0u;

  float h = 0.0f, c = 0.0f;

  #pragma unroll 1
  for (int ck = 0; ck < NCH; ck++){
    // buffer for this chunk was issued a full chunk ago -> wait is free
    asm volatile("s_waitcnt vmcnt(0)" ::: "memory");
    // issue next chunk's staging now: ~128 steps of compute to cover it
    if (ck + 1 < NCH){
      const float* src = xr + (size_t)(ck+1)*CH*7;
      float* dst = &xs[(ck+1)&1][0];
      #pragma unroll
      for (int i = 0; i < 14; i++)
        GLOAD_LDS_DW(src + i*64 + l, dst + i*64 + l);
    }
    const float* xsbuf = &xs[ck & 1][0];

    #pragma unroll 2
    for (int s = 0; s < CH; s++){
      // x for this step: uniform-address broadcast reads (hidden under dots)
      float xcv[7];
      #pragma unroll
      for (int k = 0; k < 7; k++) xcv[k] = xsbuf[s*7 + k];

      // h pairs: 8 uniform ds_read_b128 -> 32 dwords of (h_2k, h_2k+1) f16
      int hw[32];
      {
        const int4* hp = reinterpret_cast<const int4*>(hlds);
        #pragma unroll
        for (int i = 0; i < 8; i++){
          int4 v = hp[i];
          hw[4*i+0] = v.x; hw[4*i+1] = v.y; hw[4*i+2] = v.z; hw[4*i+3] = v.w;
        }
      }

      float a0 = bias[0], a1 = bias[1], a2 = bias[2], a3 = bias[3];
      #pragma unroll
      for (int k = 0; k < 7; k++){
        a0 += xcv[k]*wi[0][k];
        a1 += xcv[k]*wi[1][k];
        a2 += xcv[k]*wi[2][k];
        a3 += xcv[k]*wi[3][k];
      }

      #pragma unroll
      for (int k = 0; k < 32; k++){
        const h2 hh = __builtin_bit_cast(h2, hw[k]);
        a0 = __builtin_amdgcn_fdot2(__builtin_bit_cast(h2, wb[0][k]), hh, a0, false);
        a1 = __builtin_amdgcn_fdot2(__builtin_bit_cast(h2, wb[1][k]), hh, a1, false);
        a2 = __builtin_amdgcn_fdot2(__builtin_bit_cast(h2, wb[2][k]), hh, a2, false);
        a3 = __builtin_amdgcn_fdot2(__builtin_bit_cast(h2, wb[3][k]), hh, a3, false);
      }

      const float iv = fsig(a0);
      const float fv = fsig(a1);
      const float gv = ftanh(a2);
      const float ov = fsig(a3);

      c = fv*c + iv*gv;
      h = ov*ftanh(c);

      // publish h_{t} for next step: 2-byte store, 2-way bank alias (free)
      reinterpret_cast<unsigned short*>(hlds)[l] =
          __builtin_bit_cast(unsigned short, (_Float16)h);
    }
  }
  hout[b*HH + l] = h;
}

// Backward direction contributes only ONE step (scan reverse=True: output at
// t=T-1 is the first reverse step from zero state => W_hh_b unused, c = i*g).
// Fused with the final linear layer.
__global__ __launch_bounds__(64, 1) void lstm_bwd_lin_kernel(
    const float* __restrict__ x,   const float* __restrict__ Wib,
    const float* __restrict__ bib, const float* __restrict__ bhb,
    const float* __restrict__ Wlin,const float* __restrict__ blin,
    const float* __restrict__ hf,  float* __restrict__ out)
{
  const int b = blockIdx.x;
  const int j = threadIdx.x;  // 0..63
  const float* xt = x + ((size_t)b*TT + (TT-1))*7;
  float xv[7];
  #pragma unroll
  for (int k = 0; k < 7; k++) xv[k] = xt[k];

  float g4[4];
  #pragma unroll
  for (int qq = 0; qq < 4; qq++){
    const int g = qq*HH + j;
    float a = bib[g] + bhb[g];
    #pragma unroll
    for (int k = 0; k < 7; k++) a += xv[k]*Wib[g*7+k];
    g4[qq] = a;
  }
  const float iv = fsig(g4[0]);
  const float gv = ftanh(g4[2]);
  const float ov = fsig(g4[3]);
  const float cc = iv*gv;          // f * c0 = 0
  const float hb = ov*ftanh(cc);
  const float hfv = hf[b*HH + j];

  float s[3];
  #pragma unroll
  for (int o = 0; o < 3; o++)
    s[o] = hfv*Wlin[o*128 + j] + hb*Wlin[o*128 + 64 + j];

  #pragma unroll
  for (int o = 0; o < 3; o++){
    float v = s[o];
    #pragma unroll
    for (int m = 32; m >= 1; m >>= 1) v += __shfl_xor(v, m, 64);
    s[o] = v;
  }
  if (j == 0){
    out[b*3+0] = s[0] + blin[0];
    out[b*3+1] = s[1] + blin[1];
    out[b*3+2] = s[2] + blin[2];
  }
}

extern "C" void kernel_launch(void* const* d_in, const int* in_sizes, int n_in,
                              void* d_out, int out_size, void* d_ws, size_t ws_size,
                              hipStream_t stream)
{
  const float* x    = (const float*)d_in[0];
  const float* Wihf = (const float*)d_in[1];
  const float* Whhf = (const float*)d_in[2];
  const float* bihf = (const float*)d_in[3];
  const float* bhhf = (const float*)d_in[4];
  const float* Wihb = (const float*)d_in[5];
  // d_in[6] (W_hh_b) is mathematically unused: backward state starts at zero
  const float* bibb = (const float*)d_in[7];
  const float* bhbb = (const float*)d_in[8];
  const float* Wlin = (const float*)d_in[9];
  const float* blin = (const float*)d_in[10];
  float* out = (float*)d_out;
  float* hf  = (float*)d_ws;   // [512,64] fp32 scratch

  lstm_fwd_kernel<<<BB, 64, 0, stream>>>(x, Wihf, Whhf, bihf, bhhf, hf);
  lstm_bwd_lin_kernel<<<BB, 64, 0, stream>>>(x, Wihb, bibb, bhbb, Wlin, blin, hf, out);
}

// Round 9
// 827.129 us; speedup vs baseline: 1.7485x; 1.0393x over previous
//
#include <hip/hip_runtime.h>
#include <hip/hip_bf16.h>

#define TT 2048
#define BB 512
#define HH 64
#define L2E 1.44269504088896340736f

typedef _Float16 h2 __attribute__((ext_vector_type(2)));

__device__ __forceinline__ float frcp(float x){ return __builtin_amdgcn_rcpf(x); }
__device__ __forceinline__ float fexp2(float x){ return __builtin_amdgcn_exp2f(x); }
__device__ __forceinline__ float fsig(float a){ return frcp(1.0f + __expf(-a)); }
__device__ __forceinline__ float ftanh(float a){ return 1.0f - 2.0f*frcp(__expf(2.0f*a)+1.0f); }

// One WAVE per batch row; lane l owns hidden unit l, all 4 gates via
// v_dot2_f32_f16 on in-register f16 weight pairs; h broadcast through a
// same-wave LDS round-trip (R7, proven).
// R8: delete the per-step overhead category the R7 counters exposed
// (~400 dynamic instr/step vs ~200 static):
//  - ENTIRE x row staged to LDS once ([2048][8] f32, 64 KB) -> no chunk
//    loop, no global_load_lds/vmcnt in the recurrence, no dynamic buffer
//    pointer; x per step = 2 ds_read_b128, prefetched one step ahead.
//  - all LDS addresses loop-invariant (h base + imm offsets; x = one add).
//  - exp2-based activations: gate rows pre-scaled by -log2e (g by -2log2e)
//    so v_exp_f32 (native exp2) needs no input scaling/negation.
__global__ void __launch_bounds__(64)
__attribute__((amdgpu_waves_per_eu(1, 1)))
lstm_fwd_kernel(
    const float* __restrict__ x, const float* __restrict__ Wih,
    const float* __restrict__ Whh, const float* __restrict__ bih,
    const float* __restrict__ bhh, float* __restrict__ hout)
{
  const int b = blockIdx.x;
  const int l = threadIdx.x;   // lane == hidden unit

  __shared__ float xs[TT][8];            // 64 KB staged x (padded stride 8)
  __shared__ int4  hlds4[HH/8];          // h as f16[64] = 32 dwords, 16B-aligned

  const float* xr = x + (size_t)b*TT*7;

  // ---- one-time: stage entire x row into LDS (outside the recurrence) ----
  #pragma unroll 1
  for (int it = 0; it < TT/64; ++it){
    const int t = it*64 + l;
    const float* p = xr + (size_t)t*7;
    const float v0=p[0],v1=p[1],v2=p[2],v3=p[3],v4=p[4],v5=p[5],v6=p[6];
    float4* dst = reinterpret_cast<float4*>(&xs[t][0]);
    dst[0] = make_float4(v0,v1,v2,v3);
    dst[1] = make_float4(v4,v5,v6,0.0f);
  }

  // ---- weights: f16 pairs, pre-scaled for exp2 activations, pinned ----
  int wb[4][32];
  float wi[4][7], bias[4];
  #pragma unroll
  for (int q = 0; q < 4; q++){
    const float sq = (q==2) ? (-2.0f*L2E) : (-L2E);
    const float4* wr = reinterpret_cast<const float4*>(Whh + (size_t)(q*HH + l)*HH);
    #pragma unroll
    for (int k = 0; k < 16; k++){
      float4 a = wr[k];
      h2 p0; p0[0]=(_Float16)(a.x*sq); p0[1]=(_Float16)(a.y*sq);
      h2 p1; p1[0]=(_Float16)(a.z*sq); p1[1]=(_Float16)(a.w*sq);
      wb[q][2*k+0] = __builtin_bit_cast(int, p0);
      wb[q][2*k+1] = __builtin_bit_cast(int, p1);
    }
    const int g = q*HH + l;
    #pragma unroll
    for (int k = 0; k < 7; k++) wi[q][k] = Wih[g*7+k]*sq;
    bias[q] = (bih[g] + bhh[g])*sq;
  }
  #pragma unroll
  for (int q = 0; q < 4; q++){
    #pragma unroll
    for (int k = 0; k < 32; k++) asm volatile("" : "+v"(wb[q][k]));
    #pragma unroll
    for (int k = 0; k < 7; k++)  asm volatile("" : "+v"(wi[q][k]));
    asm volatile("" : "+v"(bias[q]));
  }

  // h_0 = 0 (single wave; DS pipe is in-order, no barrier needed)
  if (l < HH/8) hlds4[l] = int4{0,0,0,0};

  float h = 0.0f, c = 0.0f;

  // prologue: first h-read (zeros) + first x into registers
  int hw[32];
  {
    #pragma unroll
    for (int i = 0; i < 8; i++){
      int4 v = hlds4[i];
      hw[4*i+0]=v.x; hw[4*i+1]=v.y; hw[4*i+2]=v.z; hw[4*i+3]=v.w;
    }
  }
  float4 xa = *reinterpret_cast<const float4*>(&xs[0][0]);
  float4 xb = *reinterpret_cast<const float4*>(&xs[0][4]);

  #pragma unroll 2
  for (int t = 0; t < TT; ++t){
    // x-projection on current step's registers (ready; fills h-read latency)
    float a0=bias[0], a1=bias[1], a2=bias[2], a3=bias[3];
    a0 += xa.x*wi[0][0]; a1 += xa.x*wi[1][0]; a2 += xa.x*wi[2][0]; a3 += xa.x*wi[3][0];
    a0 += xa.y*wi[0][1]; a1 += xa.y*wi[1][1]; a2 += xa.y*wi[2][1]; a3 += xa.y*wi[3][1];
    a0 += xa.z*wi[0][2]; a1 += xa.z*wi[1][2]; a2 += xa.z*wi[2][2]; a3 += xa.z*wi[3][2];
    a0 += xa.w*wi[0][3]; a1 += xa.w*wi[1][3]; a2 += xa.w*wi[2][3]; a3 += xa.w*wi[3][3];
    a0 += xb.x*wi[0][4]; a1 += xb.x*wi[1][4]; a2 += xb.x*wi[2][4]; a3 += xb.x*wi[3][4];
    a0 += xb.y*wi[0][5]; a1 += xb.y*wi[1][5]; a2 += xb.y*wi[2][5]; a3 += xb.y*wi[3][5];
    a0 += xb.z*wi[0][6]; a1 += xb.z*wi[1][6]; a2 += xb.z*wi[2][6]; a3 += xb.z*wi[3][6];

    // prefetch next step's x (LDS; latency hidden under the dot phase)
    const int tn = (t+1) & (TT-1);
    const float4 xna = *reinterpret_cast<const float4*>(&xs[tn][0]);
    const float4 xnb = *reinterpret_cast<const float4*>(&xs[tn][4]);

    // recurrent dots: 128 v_dot2_f32_f16, 4 interleaved chains
    #pragma unroll
    for (int k = 0; k < 32; k++){
      const h2 hh = __builtin_bit_cast(h2, hw[k]);
      a0 = __builtin_amdgcn_fdot2(__builtin_bit_cast(h2, wb[0][k]), hh, a0, false);
      a1 = __builtin_amdgcn_fdot2(__builtin_bit_cast(h2, wb[1][k]), hh, a1, false);
      a2 = __builtin_amdgcn_fdot2(__builtin_bit_cast(h2, wb[2][k]), hh, a2, false);
      a3 = __builtin_amdgcn_fdot2(__builtin_bit_cast(h2, wb[3][k]), hh, a3, false);
    }

    // exp2-based activations (scaling folded into weights)
    const float e0 = fexp2(a0);                  // e^{-pre_i}
    const float e1 = fexp2(a1);                  // e^{-pre_f}
    const float e2 = fexp2(a2);                  // e^{-2 pre_g}
    const float e3 = fexp2(a3);                  // e^{-pre_o}
    const float iv = frcp(1.0f + e0);
    const float fv = frcp(1.0f + e1);
    const float gv = 2.0f*frcp(1.0f + e2) - 1.0f;
    const float ov = frcp(1.0f + e3);

    c = fv*c + iv*gv;
    const float th = 2.0f*frcp(1.0f + fexp2(c*(-2.0f*L2E))) - 1.0f;
    h = ov*th;

    // publish h_t (b16 store), then issue next step's h-reads (in-order DS)
    reinterpret_cast<unsigned short*>(hlds4)[l] =
        __builtin_bit_cast(unsigned short, (_Float16)h);
    #pragma unroll
    for (int i = 0; i < 8; i++){
      int4 v = hlds4[i];
      hw[4*i+0]=v.x; hw[4*i+1]=v.y; hw[4*i+2]=v.z; hw[4*i+3]=v.w;
    }

    xa = xna; xb = xnb;
  }
  hout[b*HH + l] = h;
}

// Backward direction contributes only ONE step (scan reverse=True: output at
// t=T-1 is the first reverse step from zero state => W_hh_b unused, c = i*g).
// Fused with the final linear layer.
__global__ __launch_bounds__(64, 1) void lstm_bwd_lin_kernel(
    const float* __restrict__ x,   const float* __restrict__ Wib,
    const float* __restrict__ bib, const float* __restrict__ bhb,
    const float* __restrict__ Wlin,const float* __restrict__ blin,
    const float* __restrict__ hf,  float* __restrict__ out)
{
  const int b = blockIdx.x;
  const int j = threadIdx.x;  // 0..63
  const float* xt = x + ((size_t)b*TT + (TT-1))*7;
  float xv[7];
  #pragma unroll
  for (int k = 0; k < 7; k++) xv[k] = xt[k];

  float g4[4];
  #pragma unroll
  for (int qq = 0; qq < 4; qq++){
    const int g = qq*HH + j;
    float a = bib[g] + bhb[g];
    #pragma unroll
    for (int k = 0; k < 7; k++) a += xv[k]*Wib[g*7+k];
    g4[qq] = a;
  }
  const float iv = fsig(g4[0]);
  const float gv = ftanh(g4[2]);
  const float ov = fsig(g4[3]);
  const float cc = iv*gv;          // f * c0 = 0
  const float hb = ov*ftanh(cc);
  const float hfv = hf[b*HH + j];

  float s[3];
  #pragma unroll
  for (int o = 0; o < 3; o++)
    s[o] = hfv*Wlin[o*128 + j] + hb*Wlin[o*128 + 64 + j];

  #pragma unroll
  for (int o = 0; o < 3; o++){
    float v = s[o];
    #pragma unroll
    for (int m = 32; m >= 1; m >>= 1) v += __shfl_xor(v, m, 64);
    s[o] = v;
  }
  if (j == 0){
    out[b*3+0] = s[0] + blin[0];
    out[b*3+1] = s[1] + blin[1];
    out[b*3+2] = s[2] + blin[2];
  }
}

extern "C" void kernel_launch(void* const* d_in, const int* in_sizes, int n_in,
                              void* d_out, int out_size, void* d_ws, size_t ws_size,
                              hipStream_t stream)
{
  const float* x    = (const float*)d_in[0];
  const float* Wihf = (const float*)d_in[1];
  const float* Whhf = (const float*)d_in[2];
  const float* bihf = (const float*)d_in[3];
  const float* bhhf = (const float*)d_in[4];
  const float* Wihb = (const float*)d_in[5];
  // d_in[6] (W_hh_b) is mathematically unused: backward state starts at zero
  const float* bibb = (const float*)d_in[7];
  const float* bhbb = (const float*)d_in[8];
  const float* Wlin = (const float*)d_in[9];
  const float* blin = (const float*)d_in[10];
  float* out = (float*)d_out;
  float* hf  = (float*)d_ws;   // [512,64] fp32 scratch

  lstm_fwd_kernel<<<BB, 64, 0, stream>>>(x, Wihf, Whhf, bihf, bhhf, hf);
  lstm_bwd_lin_kernel<<<BB, 64, 0, stream>>>(x, Wihb, bibb, bhbb, Wlin, blin, hf, out);
}

// Round 11
// 826.168 us; speedup vs baseline: 1.7505x; 1.0012x over previous
//
#include <hip/hip_runtime.h>
#include <hip/hip_bf16.h>

#define TT 2048
#define BB 512
#define HH 64
#define L2E 1.44269504088896340736f

typedef _Float16 h2 __attribute__((ext_vector_type(2)));

__device__ __forceinline__ float frcp(float x){ return __builtin_amdgcn_rcpf(x); }
__device__ __forceinline__ float fexp2(float x){ return __builtin_amdgcn_exp2f(x); }
__device__ __forceinline__ float fsig(float a){ return frcp(1.0f + __expf(-a)); }
__device__ __forceinline__ float ftanh(float a){ return 1.0f - 2.0f*frcp(__expf(2.0f*a)+1.0f); }
__device__ __forceinline__ h2 pk16(float lo, float hi){
  return __builtin_bit_cast(h2, __builtin_amdgcn_cvt_pkrtz(lo, hi));
}

// One WAVE per batch row; lane l owns hidden unit l, all 4 gates via
// v_dot2_f32_f16; h broadcast through same-wave LDS round-trip (R7, proven).
// R9 theory: R5-R8's flat VGPR_Count (~124-132 vs ~200 live values, no
// scratch traffic) = the weight array is PARKED IN AGPRs with a
// v_accvgpr_read bounce per dot2 (~+130 instr/step). Suspected trigger: the
// fully-unrolled init creates a >256-reg transient load spike; allocator
// resolves it by live-range-splitting into AGPRs, and the placement sticks.
// Fixes: (1) sched_barrier(0) per gate-group in init (bounded spike);
// (2) wi as f16 pairs (16 regs, was 28) + per-step cvt_pkrtz x-packing;
// (3) no x prefetch registers (2 uniform ds_read_b128/step, latency hidden
// under the 128-dot phase). Steady-state live ~185 < 256.
__global__ void __launch_bounds__(64)
__attribute__((amdgpu_waves_per_eu(1, 1)))
lstm_fwd_kernel(
    const float* __restrict__ x, const float* __restrict__ Wih,
    const float* __restrict__ Whh, const float* __restrict__ bih,
    const float* __restrict__ bhh, float* __restrict__ hout)
{
  const int b = blockIdx.x;
  const int l = threadIdx.x;   // lane == hidden unit

  __shared__ float xs[TT][8];            // 64 KB staged x (padded stride 8)
  __shared__ int4  hlds4[HH/8];          // h as f16[64] = 32 dwords

  const float* xr = x + (size_t)b*TT*7;

  // ---- one-time: stage entire x row into LDS (outside the recurrence) ----
  #pragma unroll 1
  for (int it = 0; it < TT/64; ++it){
    const int t = it*64 + l;
    const float* p = xr + (size_t)t*7;
    float4* dst = reinterpret_cast<float4*>(&xs[t][0]);
    dst[0] = make_float4(p[0],p[1],p[2],p[3]);
    dst[1] = make_float4(p[4],p[5],p[6],0.0f);   // [7] = 0 pad (x7 slot)
  }

  // ---- recurrent weights: f16 pairs, exp2 pre-scaled, pinned.
  // sched_barrier(0) after each gate bounds the transient load spike to
  // ~64 regs so the allocator never sees >256 pressure in init.
  int wb[4][32];
  #pragma unroll
  for (int q = 0; q < 4; q++){
    const float sq = (q==2) ? (-2.0f*L2E) : (-L2E);
    const float4* wr = reinterpret_cast<const float4*>(Whh + (size_t)(q*HH + l)*HH);
    #pragma unroll
    for (int k = 0; k < 16; k++){
      float4 a = wr[k];
      h2 p0 = pk16(a.x*sq, a.y*sq);
      h2 p1 = pk16(a.z*sq, a.w*sq);
      wb[q][2*k+0] = __builtin_bit_cast(int, p0);
      wb[q][2*k+1] = __builtin_bit_cast(int, p1);
      asm volatile("" : "+v"(wb[q][2*k+0]), "+v"(wb[q][2*k+1]));
    }
    __builtin_amdgcn_sched_barrier(0);
  }

  // ---- input-projection weights as f16 pairs (4 per gate) + f32 bias ----
  int wi16[4][4];
  float bias[4];
  #pragma unroll
  for (int q = 0; q < 4; q++){
    const float sq = (q==2) ? (-2.0f*L2E) : (-L2E);
    const int g = q*HH + l;
    wi16[q][0] = __builtin_bit_cast(int, pk16(Wih[g*7+0]*sq, Wih[g*7+1]*sq));
    wi16[q][1] = __builtin_bit_cast(int, pk16(Wih[g*7+2]*sq, Wih[g*7+3]*sq));
    wi16[q][2] = __builtin_bit_cast(int, pk16(Wih[g*7+4]*sq, Wih[g*7+5]*sq));
    wi16[q][3] = __builtin_bit_cast(int, pk16(Wih[g*7+6]*sq, 0.0f));
    asm volatile("" : "+v"(wi16[q][0]), "+v"(wi16[q][1]),
                       "+v"(wi16[q][2]), "+v"(wi16[q][3]));
    bias[q] = (bih[g] + bhh[g])*sq;
    asm volatile("" : "+v"(bias[q]));
    __builtin_amdgcn_sched_barrier(0);
  }

  // h_0 = 0 (single wave; DS pipe in-order, no barrier needed)
  if (l < HH/8) hlds4[l] = int4{0,0,0,0};

  float h = 0.0f, c = 0.0f;

  // prologue: first h-read (zeros)
  int hw[32];
  #pragma unroll
  for (int i = 0; i < 8; i++){
    int4 v = hlds4[i];
    hw[4*i+0]=v.x; hw[4*i+1]=v.y; hw[4*i+2]=v.z; hw[4*i+3]=v.w;
  }

  #pragma unroll 1
  for (int t = 0; t < TT; ++t){
    // x for this step: 2 uniform-address b128 reads; latency hidden under
    // the 128-dot phase (dots depend only on hw, already in registers)
    const float4 xa = *reinterpret_cast<const float4*>(&xs[t][0]);
    const float4 xb = *reinterpret_cast<const float4*>(&xs[t][4]);
    const h2 xp0 = pk16(xa.x, xa.y);
    const h2 xp1 = pk16(xa.z, xa.w);
    const h2 xp2 = pk16(xb.x, xb.y);
    const h2 xp3 = pk16(xb.z, xb.w);   // (x6, 0)

    float a0 = bias[0], a1 = bias[1], a2 = bias[2], a3 = bias[3];

    // recurrent dots first: 128 v_dot2_f32_f16 on resident hw
    #pragma unroll
    for (int k = 0; k < 32; k++){
      const h2 hh = __builtin_bit_cast(h2, hw[k]);
      a0 = __builtin_amdgcn_fdot2(__builtin_bit_cast(h2, wb[0][k]), hh, a0, false);
      a1 = __builtin_amdgcn_fdot2(__builtin_bit_cast(h2, wb[1][k]), hh, a1, false);
      a2 = __builtin_amdgcn_fdot2(__builtin_bit_cast(h2, wb[2][k]), hh, a2, false);
      a3 = __builtin_amdgcn_fdot2(__builtin_bit_cast(h2, wb[3][k]), hh, a3, false);
    }
    // input projection: 16 dot2 on packed x
    #pragma unroll
    for (int p = 0; p < 4; p++){
      const h2 xp = (p==0)?xp0:(p==1)?xp1:(p==2)?xp2:xp3;
      a0 = __builtin_amdgcn_fdot2(__builtin_bit_cast(h2, wi16[0][p]), xp, a0, false);
      a1 = __builtin_amdgcn_fdot2(__builtin_bit_cast(h2, wi16[1][p]), xp, a1, false);
      a2 = __builtin_amdgcn_fdot2(__builtin_bit_cast(h2, wi16[2][p]), xp, a2, false);
      a3 = __builtin_amdgcn_fdot2(__builtin_bit_cast(h2, wi16[3][p]), xp, a3, false);
    }

    // exp2-based activations (scaling folded into weights/bias)
    const float e0 = fexp2(a0);
    const float e1 = fexp2(a1);
    const float e2 = fexp2(a2);
    const float e3 = fexp2(a3);
    const float iv = frcp(1.0f + e0);
    const float fv = frcp(1.0f + e1);
    const float gv = 2.0f*frcp(1.0f + e2) - 1.0f;
    const float ov = frcp(1.0f + e3);

    c = fv*c + iv*gv;
    const float r  = frcp(1.0f + fexp2(c*(-2.0f*L2E)));
    h = 2.0f*ov*r - ov;          // ov * tanh(c)

    // publish h_t, then issue next step's h-reads (in-order DS, no barrier)
    reinterpret_cast<unsigned short*>(hlds4)[l] =
        __builtin_bit_cast(unsigned short, (_Float16)h);
    #pragma unroll
    for (int i = 0; i < 8; i++){
      int4 v = hlds4[i];
      hw[4*i+0]=v.x; hw[4*i+1]=v.y; hw[4*i+2]=v.z; hw[4*i+3]=v.w;
    }
  }
  hout[b*HH + l] = h;
}

// Backward direction contributes only ONE step (scan reverse=True: output at
// t=T-1 is the first reverse step from zero state => W_hh_b unused, c = i*g).
// Fused with the final linear layer.
__global__ __launch_bounds__(64, 1) void lstm_bwd_lin_kernel(
    const float* __restrict__ x,   const float* __restrict__ Wib,
    const float* __restrict__ bib, const float* __restrict__ bhb,
    const float* __restrict__ Wlin,const float* __restrict__ blin,
    const float* __restrict__ hf,  float* __restrict__ out)
{
  const int b = blockIdx.x;
  const int j = threadIdx.x;  // 0..63
  const float* xt = x + ((size_t)b*TT + (TT-1))*7;
  float xv[7];
  #pragma unroll
  for (int k = 0; k < 7; k++) xv[k] = xt[k];

  float g4[4];
  #pragma unroll
  for (int qq = 0; qq < 4; qq++){
    const int g = qq*HH + j;
    float a = bib[g] + bhb[g];
    #pragma unroll
    for (int k = 0; k < 7; k++) a += xv[k]*Wib[g*7+k];
    g4[qq] = a;
  }
  const float iv = fsig(g4[0]);
  const float gv = ftanh(g4[2]);
  const float ov = fsig(g4[3]);
  const float cc = iv*gv;          // f * c0 = 0
  const float hb = ov*ftanh(cc);
  const float hfv = hf[b*HH + j];

  float s[3];
  #pragma unroll
  for (int o = 0; o < 3; o++)
    s[o] = hfv*Wlin[o*128 + j] + hb*Wlin[o*128 + 64 + j];

  #pragma unroll
  for (int o = 0; o < 3; o++){
    float v = s[o];
    #pragma unroll
    for (int m = 32; m >= 1; m >>= 1) v += __shfl_xor(v, m, 64);
    s[o] = v;
  }
  if (j == 0){
    out[b*3+0] = s[0] + blin[0];
    out[b*3+1] = s[1] + blin[1];
    out[b*3+2] = s[2] + blin[2];
  }
}

extern "C" void kernel_launch(void* const* d_in, const int* in_sizes, int n_in,
                              void* d_out, int out_size, void* d_ws, size_t ws_size,
                              hipStream_t stream)
{
  const float* x    = (const float*)d_in[0];
  const float* Wihf = (const float*)d_in[1];
  const float* Whhf = (const float*)d_in[2];
  const float* bihf = (const float*)d_in[3];
  const float* bhhf = (const float*)d_in[4];
  const float* Wihb = (const float*)d_in[5];
  // d_in[6] (W_hh_b) is mathematically unused: backward state starts at zero
  const float* bibb = (const float*)d_in[7];
  const float* bhbb = (const float*)d_in[8];
  const float* Wlin = (const float*)d_in[9];
  const float* blin = (const float*)d_in[10];
  float* out = (float*)d_out;
  float* hf  = (float*)d_ws;   // [512,64] fp32 scratch

  lstm_fwd_kernel<<<BB, 64, 0, stream>>>(x, Wihf, Whhf, bihf, bhhf, hf);
  lstm_bwd_lin_kernel<<<BB, 64, 0, stream>>>(x, Wihb, bibb, bhbb, Wlin, blin, hf, out);
}

// Round 12
// 796.740 us; speedup vs baseline: 1.8152x; 1.0369x over previous
//
#include <hip/hip_runtime.h>
#include <hip/hip_bf16.h>

#define TT 2048
#define BB 512
#define HH 64
#define L2E 1.44269504088896340736f

typedef _Float16 h2 __attribute__((ext_vector_type(2)));

__device__ __forceinline__ float frcp(float x){ return __builtin_amdgcn_rcpf(x); }
__device__ __forceinline__ float fexp2(float x){ return __builtin_amdgcn_exp2f(x); }
__device__ __forceinline__ float fsig(float a){ return frcp(1.0f + __expf(-a)); }
__device__ __forceinline__ float ftanh(float a){ return 1.0f - 2.0f*frcp(__expf(2.0f*a)+1.0f); }
__device__ __forceinline__ h2 pk16(float lo, float hi){
  return __builtin_bit_cast(h2, __builtin_amdgcn_cvt_pkrtz(lo, hi));
}
__device__ __forceinline__ float dot2(int w, int hp, float acc){
  return __builtin_amdgcn_fdot2(__builtin_bit_cast(h2, w),
                                __builtin_bit_cast(h2, hp), acc, false);
}

// One WAVE per batch row; lane l owns hidden unit l; all 4 gate dots via
// v_dot2_f32_f16; h broadcast via same-wave LDS round-trip (R7, proven).
// R11 pivot: stop fighting the register allocator (R5-R10: VGPR_Count frozen
// at ~132 across every pinning strategy; the overflow weight dwords get
// bounced through the unified file every step). Weight sourcing is now split
// between the two storages WE control:
//   - gates i,f: 64 dwords in registers (R2's proven-resident regime)
//   - gates g,o: LDS, [gate][kb][lane] int4 layout -> contiguous-16B/lane
//     ds_read_b128 (canonical conflict-free), 16 reads/step issued a phase
//     early so dot-issue covers their latency; LDS pipe streams in parallel
//     with the VALU dot chain.
//   - x staged once as f16 pairs: one uniform b128/step, pre-packed for dot2.
__global__ void __launch_bounds__(64)
__attribute__((amdgpu_waves_per_eu(1, 2)))
lstm_fwd_kernel(
    const float* __restrict__ x, const float* __restrict__ Wih,
    const float* __restrict__ Whh, const float* __restrict__ bih,
    const float* __restrict__ bhh, float* __restrict__ hout)
{
  const int b = blockIdx.x;
  const int l = threadIdx.x;   // lane == hidden unit

  __shared__ int4 xsf4[TT];          // x as f16 pairs: 16B/step = 32 KB
  __shared__ int4 wgo[2][8][HH];     // g,o weights: [gate][kb][lane] = 16 KB
  __shared__ int4 hlds4[HH/8];       // h as f16[64] = 128 B

  const float* xr = x + (size_t)b*TT*7;

  // ---- one-time: stage x row as f16 pairs (raw; scale lives in wi16) ----
  #pragma unroll 1
  for (int it = 0; it < TT/64; ++it){
    const int t = it*64 + l;
    const float* p = xr + (size_t)t*7;
    int4 v;
    v.x = __builtin_bit_cast(int, pk16(p[0], p[1]));
    v.y = __builtin_bit_cast(int, pk16(p[2], p[3]));
    v.z = __builtin_bit_cast(int, pk16(p[4], p[5]));
    v.w = __builtin_bit_cast(int, pk16(p[6], 0.0f));
    xsf4[t] = v;
  }

  // ---- one-time: stage g,o recurrent weights into LDS (exp2 pre-scaled) ----
  #pragma unroll
  for (int g = 0; g < 2; ++g){
    const int q = 2 + g;                       // 2:g 3:o
    const float sq = (q == 2) ? (-2.0f*L2E) : (-L2E);
    const float4* wr = reinterpret_cast<const float4*>(Whh + (size_t)(q*HH + l)*HH);
    #pragma unroll
    for (int kb = 0; kb < 8; ++kb){
      float4 a = wr[2*kb], b4 = wr[2*kb+1];
      int4 v;
      v.x = __builtin_bit_cast(int, pk16(a.x*sq,  a.y*sq));
      v.y = __builtin_bit_cast(int, pk16(a.z*sq,  a.w*sq));
      v.z = __builtin_bit_cast(int, pk16(b4.x*sq, b4.y*sq));
      v.w = __builtin_bit_cast(int, pk16(b4.z*sq, b4.w*sq));
      wgo[g][kb][l] = v;
    }
  }

  // ---- i,f recurrent weights in registers (64 dwords, pinned) ----
  int wbi[32], wbf[32];
  {
    const float4* wri = reinterpret_cast<const float4*>(Whh + (size_t)(0*HH + l)*HH);
    const float4* wrf = reinterpret_cast<const float4*>(Whh + (size_t)(1*HH + l)*HH);
    #pragma unroll
    for (int k = 0; k < 16; k++){
      float4 a = wri[k];
      wbi[2*k+0] = __builtin_bit_cast(int, pk16(a.x*(-L2E), a.y*(-L2E)));
      wbi[2*k+1] = __builtin_bit_cast(int, pk16(a.z*(-L2E), a.w*(-L2E)));
      asm volatile("" : "+v"(wbi[2*k+0]), "+v"(wbi[2*k+1]));
    }
    __builtin_amdgcn_sched_barrier(0);
    #pragma unroll
    for (int k = 0; k < 16; k++){
      float4 a = wrf[k];
      wbf[2*k+0] = __builtin_bit_cast(int, pk16(a.x*(-L2E), a.y*(-L2E)));
      wbf[2*k+1] = __builtin_bit_cast(int, pk16(a.z*(-L2E), a.w*(-L2E)));
      asm volatile("" : "+v"(wbf[2*k+0]), "+v"(wbf[2*k+1]));
    }
    __builtin_amdgcn_sched_barrier(0);
  }

  // ---- input-projection weights as f16 pairs + f32 bias ----
  int wi16[4][4];
  float bias[4];
  #pragma unroll
  for (int q = 0; q < 4; q++){
    const float sq = (q==2) ? (-2.0f*L2E) : (-L2E);
    const int g = q*HH + l;
    wi16[q][0] = __builtin_bit_cast(int, pk16(Wih[g*7+0]*sq, Wih[g*7+1]*sq));
    wi16[q][1] = __builtin_bit_cast(int, pk16(Wih[g*7+2]*sq, Wih[g*7+3]*sq));
    wi16[q][2] = __builtin_bit_cast(int, pk16(Wih[g*7+4]*sq, Wih[g*7+5]*sq));
    wi16[q][3] = __builtin_bit_cast(int, pk16(Wih[g*7+6]*sq, 0.0f));
    bias[q] = (bih[g] + bhh[g])*sq;
  }

  // h_0 = 0 (single wave; per-wave DS ordering makes this visible below)
  if (l < HH/8) hlds4[l] = int4{0,0,0,0};

  float h = 0.0f, c = 0.0f;

  // prologue: first h-read (zeros)
  int hw[32];
  #pragma unroll
  for (int i = 0; i < 8; i++){
    int4 v = hlds4[i];
    hw[4*i+0]=v.x; hw[4*i+1]=v.y; hw[4*i+2]=v.z; hw[4*i+3]=v.w;
  }

  #pragma unroll 1
  for (int t = 0; t < TT; ++t){
    // x pairs for this step: one uniform broadcast b128
    const int4 xv = xsf4[t];

    // issue g-gate weight reads now; i/f dot phase (~128 cyc) covers latency
    int4 g0 = wgo[0][0][l], g1 = wgo[0][1][l], g2 = wgo[0][2][l], g3 = wgo[0][3][l];
    int4 g4 = wgo[0][4][l], g5 = wgo[0][5][l], g6 = wgo[0][6][l], g7 = wgo[0][7][l];

    float a0 = bias[0], a1 = bias[1], a2 = bias[2], a3 = bias[3];

    // i,f dots on register weights (64 dot2)
    #pragma unroll
    for (int k = 0; k < 32; k++){
      a0 = dot2(wbi[k], hw[k], a0);
      a1 = dot2(wbf[k], hw[k], a1);
    }

    // issue o-gate weight reads; g dot phase covers most of their latency
    int4 o0 = wgo[1][0][l], o1 = wgo[1][1][l], o2 = wgo[1][2][l], o3 = wgo[1][3][l];
    int4 o4 = wgo[1][4][l], o5 = wgo[1][5][l], o6 = wgo[1][6][l], o7 = wgo[1][7][l];

    // g dots (32 dot2) on LDS-sourced weights
    #define GDOT(gg, kb) \
      a2 = dot2((gg).x, hw[4*(kb)+0], a2); \
      a2 = dot2((gg).y, hw[4*(kb)+1], a2); \
      a2 = dot2((gg).z, hw[4*(kb)+2], a2); \
      a2 = dot2((gg).w, hw[4*(kb)+3], a2);
    GDOT(g0,0) GDOT(g1,1) GDOT(g2,2) GDOT(g3,3)
    GDOT(g4,4) GDOT(g5,5) GDOT(g6,6) GDOT(g7,7)
    #undef GDOT

    // o dots (32 dot2)
    #define ODOT(oo, kb) \
      a3 = dot2((oo).x, hw[4*(kb)+0], a3); \
      a3 = dot2((oo).y, hw[4*(kb)+1], a3); \
      a3 = dot2((oo).z, hw[4*(kb)+2], a3); \
      a3 = dot2((oo).w, hw[4*(kb)+3], a3);
    ODOT(o0,0) ODOT(o1,1) ODOT(o2,2) ODOT(o3,3)
    ODOT(o4,4) ODOT(o5,5) ODOT(o6,6) ODOT(o7,7)
    #undef ODOT

    // input projection: 16 dot2 on packed x
    a0 = dot2(wi16[0][0], xv.x, a0); a0 = dot2(wi16[0][1], xv.y, a0);
    a0 = dot2(wi16[0][2], xv.z, a0); a0 = dot2(wi16[0][3], xv.w, a0);
    a1 = dot2(wi16[1][0], xv.x, a1); a1 = dot2(wi16[1][1], xv.y, a1);
    a1 = dot2(wi16[1][2], xv.z, a1); a1 = dot2(wi16[1][3], xv.w, a1);
    a2 = dot2(wi16[2][0], xv.x, a2); a2 = dot2(wi16[2][1], xv.y, a2);
    a2 = dot2(wi16[2][2], xv.z, a2); a2 = dot2(wi16[2][3], xv.w, a2);
    a3 = dot2(wi16[3][0], xv.x, a3); a3 = dot2(wi16[3][1], xv.y, a3);
    a3 = dot2(wi16[3][2], xv.z, a3); a3 = dot2(wi16[3][3], xv.w, a3);

    // exp2-based activations (scaling folded into weights/bias)
    const float e0 = fexp2(a0);
    const float e1 = fexp2(a1);
    const float e2 = fexp2(a2);
    const float e3 = fexp2(a3);
    const float iv = frcp(1.0f + e0);
    const float fv = frcp(1.0f + e1);
    const float gv = 2.0f*frcp(1.0f + e2) - 1.0f;
    const float ov = frcp(1.0f + e3);

    c = fv*c + iv*gv;
    const float r = frcp(1.0f + fexp2(c*(-2.0f*L2E)));
    h = 2.0f*ov*r - ov;          // ov * tanh(c)

    // publish h_t, then issue next step's h-reads (per-wave in-order DS)
    reinterpret_cast<unsigned short*>(hlds4)[l] =
        __builtin_bit_cast(unsigned short, (_Float16)h);
    #pragma unroll
    for (int i = 0; i < 8; i++){
      int4 v = hlds4[i];
      hw[4*i+0]=v.x; hw[4*i+1]=v.y; hw[4*i+2]=v.z; hw[4*i+3]=v.w;
    }
  }
  hout[b*HH + l] = h;
}

// Backward direction contributes only ONE step (scan reverse=True: output at
// t=T-1 is the first reverse step from zero state => W_hh_b unused, c = i*g).
// Fused with the final linear layer.
__global__ __launch_bounds__(64, 1) void lstm_bwd_lin_kernel(
    const float* __restrict__ x,   const float* __restrict__ Wib,
    const float* __restrict__ bib, const float* __restrict__ bhb,
    const float* __restrict__ Wlin,const float* __restrict__ blin,
    const float* __restrict__ hf,  float* __restrict__ out)
{
  const int b = blockIdx.x;
  const int j = threadIdx.x;  // 0..63
  const float* xt = x + ((size_t)b*TT + (TT-1))*7;
  float xv[7];
  #pragma unroll
  for (int k = 0; k < 7; k++) xv[k] = xt[k];

  float g4[4];
  #pragma unroll
  for (int qq = 0; qq < 4; qq++){
    const int g = qq*HH + j;
    float a = bib[g] + bhb[g];
    #pragma unroll
    for (int k = 0; k < 7; k++) a += xv[k]*Wib[g*7+k];
    g4[qq] = a;
  }
  const float iv = fsig(g4[0]);
  const float gv = ftanh(g4[2]);
  const float ov = fsig(g4[3]);
  const float cc = iv*gv;          // f * c0 = 0
  const float hb = ov*ftanh(cc);
  const float hfv = hf[b*HH + j];

  float s[3];
  #pragma unroll
  for (int o = 0; o < 3; o++)
    s[o] = hfv*Wlin[o*128 + j] + hb*Wlin[o*128 + 64 + j];

  #pragma unroll
  for (int o = 0; o < 3; o++){
    float v = s[o];
    #pragma unroll
    for (int m = 32; m >= 1; m >>= 1) v += __shfl_xor(v, m, 64);
    s[o] = v;
  }
  if (j == 0){
    out[b*3+0] = s[0] + blin[0];
    out[b*3+1] = s[1] + blin[1];
    out[b*3+2] = s[2] + blin[2];
  }
}

extern "C" void kernel_launch(void* const* d_in, const int* in_sizes, int n_in,
                              void* d_out, int out_size, void* d_ws, size_t ws_size,
                              hipStream_t stream)
{
  const float* x    = (const float*)d_in[0];
  const float* Wihf = (const float*)d_in[1];
  const float* Whhf = (const float*)d_in[2];
  const float* bihf = (const float*)d_in[3];
  const float* bhhf = (const float*)d_in[4];
  const float* Wihb = (const float*)d_in[5];
  // d_in[6] (W_hh_b) is mathematically unused: backward state starts at zero
  const float* bibb = (const float*)d_in[7];
  const float* bhbb = (const float*)d_in[8];
  const float* Wlin = (const float*)d_in[9];
  const float* blin = (const float*)d_in[10];
  float* out = (float*)d_out;
  float* hf  = (float*)d_ws;   // [512,64] fp32 scratch

  lstm_fwd_kernel<<<BB, 64, 0, stream>>>(x, Wihf, Whhf, bihf, bhhf, hf);
  lstm_bwd_lin_kernel<<<BB, 64, 0, stream>>>(x, Wihb, bibb, bhbb, Wlin, blin, hf, out);
}